// Round 14
// baseline (202.597 us; speedup 1.0000x reference)
//
#include <hip/hip_runtime.h>
#include <math.h>

// ---------------------------------------------------------------------------
// AttentionLayer: out = softmax(mask(q k^T * scale)) @ v,  q/k/v = x@W + b
// B=4, T=2048, C=H=768.  bf16 MFMA (16x16x32), fp32 accumulate.
// R17 = R16 + split-K o_gemm.  Residency model (validated vs R13/R15/R16
//     measurements): s/o grids fit fully co-resident (<768 blocks), so
//     kernel duration = LONGEST block, not work/machine.  o's causal K
//     spans 4..64 k-tiles -> pinned at 64 while avg is 34; the R6 balance
//     pairing is useless under co-residency.  Fix: ti>=8 blocks split into
//     two K-halves (both even, gemm_core untouched); half 0 writes out,
//     half 1 writes a partial buffer; combine kernel adds partials into
//     rows [1024,2048) per batch.  Grid 384->576 (still co-resident),
//     critical path 64->32 k-tiles.  Everything else identical to R16.
// ---------------------------------------------------------------------------

#define BB 4
#define TT 2048
#define CC 768

typedef __bf16 bf16_t;
typedef __bf16 bf16x8 __attribute__((ext_vector_type(8)));
typedef _Float16 half8 __attribute__((ext_vector_type(8)));
typedef float f32x4 __attribute__((ext_vector_type(4)));

// ---------------------------------------------------------------------------
// async global->LDS 16B copy (wave-uniform LDS base + lane*16 implicit)
// ---------------------------------------------------------------------------
__device__ __forceinline__ void async_load16(void* lds, const void* g) {
  __builtin_amdgcn_global_load_lds(
      (const __attribute__((address_space(1))) void*)g,
      (__attribute__((address_space(3))) void*)lds, 16, 0, 0);
}

// Chunk swizzle for a 128x32 bf16 tile stored as 4x16B chunks per 64B row.
__device__ __forceinline__ int swz4(int r) {
  return (r & 3) ^ ((r >> 2) & 3);
}

// Stage a 128x32 bf16 tile (row-major, row stride ld elements) into LDS.
__device__ __forceinline__ void stage_tile(const bf16_t* __restrict__ g0,
                                           int ld, bf16_t* lds, int t) {
  int w = t >> 6, l = t & 63;
#pragma unroll
  for (int i = 0; i < 2; ++i) {
    int c = i * 256 + w * 64 + l;   // linear 16B-chunk id in LDS
    int row = c >> 2;
    int p = c & 3;
    int q = p ^ swz4(row);          // logical chunk to fetch
    async_load16(lds + i * 2048 + w * 512,  // wave-uniform base (elements)
                 g0 + row * ld + q * 8);
  }
}

// Read one MFMA fragment (8 bf16, 16B) for logical (row r, k-chunk q).
__device__ __forceinline__ bf16x8 read_frag(const bf16_t* lds, int r, int q) {
  int p = q ^ swz4(r);
  return *(const bf16x8*)(lds + r * 32 + p * 8);
}

// One 128x128x32 MFMA step from a published LDS buffer pair.
__device__ __forceinline__ void mfma_tile(const bf16_t* Ab, const bf16_t* Bb,
                                          int wr, int wc, int l,
                                          f32x4 acc[4][4]) {
  bf16x8 af[4], bfr[4];
  int q = l >> 4;
#pragma unroll
  for (int i = 0; i < 4; ++i) {
    af[i] = read_frag(Ab, wr + i * 16 + (l & 15), q);
    bfr[i] = read_frag(Bb, wc + i * 16 + (l & 15), q);
  }
#pragma unroll
  for (int mi = 0; mi < 4; ++mi)
#pragma unroll
    for (int ni = 0; ni < 4; ++ni)
      acc[mi][ni] = __builtin_amdgcn_mfma_f32_16x16x32_bf16(
          af[mi], bfr[ni], acc[mi][ni], 0, 0, 0);
}

// Core: C[128x128] += A[128xK] * B^T.  kTiles must be EVEN.
// R3-proven unroll-2 static double-buffer: one barrier per k-tile; each async
// stage has a full MFMA phase in flight before the barrier that drains it.
// Plain __syncthreads (compiler manages waitcnt); 32 KB LDS.
__device__ __forceinline__ void gemm_core(const bf16_t* __restrict__ A, int lda,
                                          const bf16_t* __restrict__ B, int ldb,
                                          int kTiles, bf16_t* As0, bf16_t* As1,
                                          bf16_t* Bs0, bf16_t* Bs1,
                                          f32x4 acc[4][4]) {
  int t = threadIdx.x;
  int l = t & 63;
  int w = t >> 6;
  int wr = (w >> 1) * 64;  // wave row offset in 128-tile
  int wc = (w & 1) * 64;   // wave col offset

  stage_tile(A, lda, As0, t);  // k-tile 0 -> buf0
  stage_tile(B, ldb, Bs0, t);

  for (int kt = 0; kt < kTiles; kt += 2) {
    __syncthreads();  // publish buf0(kt); prior buf1 reads complete
    stage_tile(A + (kt + 1) * 32, lda, As1, t);   // prefetch kt+1
    stage_tile(B + (kt + 1) * 32, ldb, Bs1, t);
    mfma_tile(As0, Bs0, wr, wc, l, acc);
    __syncthreads();  // publish buf1(kt+1); buf0 reads complete
    if (kt + 2 < kTiles) {
      stage_tile(A + (kt + 2) * 32, lda, As0, t);  // prefetch kt+2
      stage_tile(B + (kt + 2) * 32, ldb, Bs0, t);
    }
    mfma_tile(As1, Bs1, wr, wc, l, acc);
  }
}

// C/D layout (m89-verified): col = lane&15, row = (lane>>4)*4 + reg.

// ---------------------------------------------------------------------------
// Kernel 1: cast x (fp32) -> bf16, 8 elems/thread
// ---------------------------------------------------------------------------
__global__ __launch_bounds__(256) void cast_x_kernel(
    const float* __restrict__ x, bf16_t* __restrict__ xbf) {
  int i = blockIdx.x * 256 + threadIdx.x;
  const float4* xin = (const float4*)x;
  float4 a = xin[i * 2];
  float4 b = xin[i * 2 + 1];
  bf16_t tmp[8];
  tmp[0] = (bf16_t)a.x; tmp[1] = (bf16_t)a.y;
  tmp[2] = (bf16_t)a.z; tmp[3] = (bf16_t)a.w;
  tmp[4] = (bf16_t)b.x; tmp[5] = (bf16_t)b.y;
  tmp[6] = (bf16_t)b.z; tmp[7] = (bf16_t)b.w;
  *(uint4*)(xbf + (size_t)i * 8) = *(const uint4*)tmp;
}

// ---------------------------------------------------------------------------
// Kernel 2: transpose+cast the three weight matrices [C][H] -> bf16 [H][C]
// ---------------------------------------------------------------------------
__global__ __launch_bounds__(256) void transpose_w_kernel(
    const float* __restrict__ Wq, const float* __restrict__ Wk,
    const float* __restrict__ Wv, bf16_t* __restrict__ wt) {
  int z = blockIdx.z;
  const float* W = (z == 0) ? Wq : (z == 1) ? Wk : Wv;
  bf16_t* out = wt + (size_t)z * CC * CC;
  __shared__ float tile[32][33];
  int tx = threadIdx.x;  // 0..31
  int ty = threadIdx.y;  // 0..7
  int n0 = blockIdx.x * 32;
  int c0 = blockIdx.y * 32;
#pragma unroll
  for (int k = 0; k < 4; ++k)
    tile[ty + k * 8][tx] = W[(size_t)(c0 + ty + k * 8) * CC + n0 + tx];
  __syncthreads();
#pragma unroll
  for (int k = 0; k < 4; ++k)
    out[(size_t)(n0 + ty + k * 8) * CC + c0 + tx] =
        (bf16_t)tile[tx][ty + k * 8];
}

// ---------------------------------------------------------------------------
// Kernel 3: QKV GEMM, 1D grid of 1152 = 8 XCD chunks x 144.
// Chunk-local order: n fastest within an m-row -> the 6 blocks sharing an
// A m-tile run consecutively on ONE XCD (L2 catches the re-reads).
// z=0: q (scaled by H^-1/2, direct stores), z=1: k (direct stores),
// z=2: v transposed (LDS-coalesced 16B stores).
// ---------------------------------------------------------------------------
__global__ __launch_bounds__(256) void qkv_gemm_kernel(
    const bf16_t* __restrict__ xbf, const bf16_t* __restrict__ wt,
    const float* __restrict__ bq, const float* __restrict__ bk,
    const float* __restrict__ bv, bf16_t* __restrict__ qb,
    bf16_t* __restrict__ kb, bf16_t* __restrict__ vt) {
  __shared__ bf16_t smem[16384];  // 32KB: gemm dbuf, then vt transpose buf
  int bid = blockIdx.x;
  int work = (bid & 7) * 144 + (bid >> 3);  // 1152 = 8 * 144 (bijective)
  int z = work / 384;
  int rw = work - z * 384;
  int m0 = (rw / 6) * 128;
  int n0 = (rw % 6) * 128;

  f32x4 acc[4][4];
#pragma unroll
  for (int i = 0; i < 4; ++i)
#pragma unroll
    for (int j = 0; j < 4; ++j) acc[i][j] = (f32x4){0.f, 0.f, 0.f, 0.f};

  const bf16_t* A = xbf + (size_t)m0 * CC;
  const bf16_t* B = wt + (size_t)z * CC * CC + (size_t)n0 * CC;
  gemm_core(A, CC, B, CC, CC / 32, smem, smem + 4096, smem + 8192,
            smem + 12288, acc);

  int t = threadIdx.x;
  int l = t & 63, w = t >> 6;
  int wr = (w >> 1) * 64, wc = (w & 1) * 64;
  const float* bias = (z == 0) ? bq : (z == 1) ? bk : bv;

  if (z < 2) {
    float scale = (z == 0) ? rsqrtf((float)CC) : 1.0f;
    bf16_t* dst = (z == 0) ? qb : kb;
#pragma unroll
    for (int mi = 0; mi < 4; ++mi) {
#pragma unroll
      for (int ni = 0; ni < 4; ++ni) {
        int col = n0 + wc + ni * 16 + (l & 15);
        int rbase = m0 + wr + mi * 16 + (l >> 4) * 4;
        float bcol = bias[col];
#pragma unroll
        for (int r = 0; r < 4; ++r) {
          float v = (acc[mi][ni][r] + bcol) * scale;
          dst[(size_t)(rbase + r) * CC + col] = (bf16_t)v;
        }
      }
    }
  } else {
    // v^T: stage as [col][m] (chunk-XOR), write 16B/lane along T.
    __syncthreads();  // all waves done reading gemm LDS buffers
#pragma unroll
    for (int mi = 0; mi < 4; ++mi) {
#pragma unroll
      for (int ni = 0; ni < 4; ++ni) {
        int cl = wc + ni * 16 + (l & 15);
        int mlb = wr + mi * 16 + (l >> 4) * 4;
        float bcol = bias[n0 + cl];
        bf16_t t4[4];
#pragma unroll
        for (int r = 0; r < 4; ++r) t4[r] = (bf16_t)(acc[mi][ni][r] + bcol);
        int e = cl * 128 + (((mlb >> 3) ^ (cl & 15)) << 3) + (mlb & 7);
        *(uint2*)((unsigned int*)smem + (e >> 1)) = *(const uint2*)t4;
      }
    }
    __syncthreads();
    int b = m0 >> 11;
    int tt0 = m0 & (TT - 1);
#pragma unroll
    for (int g = 0; g < 8; ++g) {
      int cl = g * 16 + (t >> 4);
      int ck = t & 15;
      int phys = ck ^ (cl & 15);
      uint4 v = *(const uint4*)(smem + cl * 128 + phys * 8);
      *(uint4*)(vt + ((size_t)b * CC + n0 + cl) * TT + tt0 + ck * 8) = v;
    }
  }
}

// ---------------------------------------------------------------------------
// Kernel 4: S = q k^T (scale folded into q), causal mask + (==0 -> -inf),
// stored fp16.  1D grid of 544 LIVE lower-tri blocks = 8 XCD chunks x 68;
// triangular decode (guarded sqrt).  Same-ti blocks consecutive -> q-tile
// L2 reuse.
// ---------------------------------------------------------------------------
__global__ __launch_bounds__(256, 4) void s_gemm_kernel(
    const bf16_t* __restrict__ qb, const bf16_t* __restrict__ kb,
    _Float16* __restrict__ S) {
  __shared__ bf16_t As0[4096], As1[4096], Bs0[4096], Bs1[4096];
  int bid = blockIdx.x;
  int work = (bid & 7) * 68 + (bid >> 3);  // 544 = 8 * 68 (bijective)
  int b = work / 136;
  int t = work - b * 136;
  int ti = (int)((sqrtf(8.f * (float)t + 1.f) - 1.f) * 0.5f);
  while ((ti + 1) * (ti + 2) / 2 <= t) ++ti;  // guard fp rounding
  while (ti * (ti + 1) / 2 > t) --ti;
  int tj = t - ti * (ti + 1) / 2;
  int m0 = ti * 128, n0 = tj * 128;

  f32x4 acc[4][4];
#pragma unroll
  for (int i = 0; i < 4; ++i)
#pragma unroll
    for (int j = 0; j < 4; ++j) acc[i][j] = (f32x4){0.f, 0.f, 0.f, 0.f};

  const bf16_t* A = qb + ((size_t)b * TT + m0) * CC;
  const bf16_t* B = kb + ((size_t)b * TT + n0) * CC;
  gemm_core(A, CC, B, CC, CC / 32, As0, As1, Bs0, Bs1, acc);

  _Float16* Sb = S + (size_t)b * TT * TT;
  int l = threadIdx.x & 63, w = threadIdx.x >> 6;
  int wr = (w >> 1) * 64, wc = (w & 1) * 64;
#pragma unroll
  for (int mi = 0; mi < 4; ++mi) {
#pragma unroll
    for (int ni = 0; ni < 4; ++ni) {
      int j = n0 + wc + ni * 16 + (l & 15);
      int ibase = m0 + wr + mi * 16 + (l >> 4) * 4;
#pragma unroll
      for (int r = 0; r < 4; ++r) {
        int i = ibase + r;
        float v = acc[mi][ni][r];
        if (j > i || v == 0.0f) v = -INFINITY;  // causal + reference quirk
        Sb[(size_t)i * TT + j] = (_Float16)v;
      }
    }
  }
}

// ---------------------------------------------------------------------------
// Kernel 5: rowstat+normalize, wave-per-row (no LDS, no barriers).
// Block = 4 waves = 4 rows.  Per row: max M, L = sum exp(s-M); writes
// P = exp(s-M)/L as bf16 up to the 128-padded causal length.
// Lane l covers chunks {l, l+64, l+128, l+192} of 8 fp16 each.
// ---------------------------------------------------------------------------
__global__ __launch_bounds__(256) void rowstat_kernel(
    const _Float16* __restrict__ S, bf16_t* __restrict__ P) {
  int g = blockIdx.x * 4 + (threadIdx.x >> 6);  // global row id
  int b = g >> 11;
  int row = g & (TT - 1);
  int l = threadIdx.x & 63;
  const _Float16* s = S + ((size_t)b * TT + row) * TT;
  bf16_t* p = P + ((size_t)b * TT + row) * TT;
  int pe = ((row >> 7) + 1) << 7;  // padded causal length, multiple of 128

  float f[4][8];
#pragma unroll
  for (int c = 0; c < 4; ++c) {
    int j = (c * 64 + l) * 8;
    if (j < pe) {
      half8 h = *(const half8*)(s + j);
#pragma unroll
      for (int k = 0; k < 8; ++k) f[c][k] = (float)h[k];
    } else {
#pragma unroll
      for (int k = 0; k < 8; ++k) f[c][k] = -INFINITY;
    }
  }

  float m = f[0][0];
#pragma unroll
  for (int c = 0; c < 4; ++c)
#pragma unroll
    for (int k = 0; k < 8; ++k) m = fmaxf(m, f[c][k]);
#pragma unroll
  for (int off = 32; off > 0; off >>= 1) m = fmaxf(m, __shfl_xor(m, off));

  float e[4][8];
  float sum = 0.f;
#pragma unroll
  for (int c = 0; c < 4; ++c)
#pragma unroll
    for (int k = 0; k < 8; ++k) {
      e[c][k] = __expf(f[c][k] - m);  // exp(-inf)=0 for masked slots
      sum += e[c][k];
    }
#pragma unroll
  for (int off = 32; off > 0; off >>= 1) sum += __shfl_xor(sum, off);
  float inv = 1.0f / sum;

#pragma unroll
  for (int c = 0; c < 4; ++c) {
    int j = (c * 64 + l) * 8;
    if (j < pe) {
      bf16x8 o;
#pragma unroll
      for (int k = 0; k < 8; ++k) o[k] = (bf16_t)(e[c][k] * inv);
      *(bf16x8*)(p + j) = o;
    }
  }
}

// ---------------------------------------------------------------------------
// Kernel 6: O = P @ V   (A = P row-major [T][T], Bt = v^T [B][H][T]).
// Split-K: ti<8 -> one block (kt=(ti+1)*4 <= 32); ti>=8 -> two blocks, each
// kt=2(ti+1) <= 32 (even).  half 0 writes out; half 1 writes the partial
// buffer (rows [1024,2048) per batch), combined by combine_kernel.
// 1D grid of 576 = 8 XCD chunks x 72 (all co-resident; crit path 32 kt).
// ---------------------------------------------------------------------------
__global__ __launch_bounds__(256, 4) void o_gemm_kernel(
    const bf16_t* __restrict__ P, const bf16_t* __restrict__ vt,
    float* __restrict__ out, float* __restrict__ part) {
  __shared__ bf16_t As0[4096], As1[4096], Bs0[4096], Bs1[4096];
  int bid = blockIdx.x;
  int work = (bid & 7) * 72 + (bid >> 3);  // 576 = 8 * 72 (bijective)
  int b = work / 144;
  int j = work - b * 144;
  int ti, nj, half, kstart, kt;
  if (j < 48) {                    // ti 0..7, unsplit
    ti = j / 6;
    nj = j - ti * 6;
    half = 0;
    kstart = 0;
    kt = (ti + 1) * 4;             // 4..32, even
  } else {                         // ti 8..15, two K-halves
    int j2 = j - 48;               // 0..95 = 8 ti x 6 nj x 2 halves
    ti = 8 + j2 / 12;
    int s = j2 - (ti - 8) * 12;
    nj = s >> 1;
    half = s & 1;
    kt = (ti + 1) * 2;             // 18..32, even
    kstart = half ? kt : 0;
  }
  int m0 = ti * 128, n0 = nj * 128;

  f32x4 acc[4][4];
#pragma unroll
  for (int ii = 0; ii < 4; ++ii)
#pragma unroll
    for (int jj = 0; jj < 4; ++jj) acc[ii][jj] = (f32x4){0.f, 0.f, 0.f, 0.f};

  const bf16_t* A = P + ((size_t)b * TT + m0) * TT + kstart * 32;
  const bf16_t* B = vt + ((size_t)b * CC + n0) * TT + kstart * 32;
  gemm_core(A, TT, B, TT, kt, As0, As1, Bs0, Bs1, acc);

  int l = threadIdx.x & 63, w = threadIdx.x >> 6;
  int wr = (w >> 1) * 64, wc = (w & 1) * 64;
  if (half == 0) {
    float* Ob = out + (size_t)b * TT * CC;
#pragma unroll
    for (int mi = 0; mi < 4; ++mi) {
#pragma unroll
      for (int ni = 0; ni < 4; ++ni) {
        int col = n0 + wc + ni * 16 + (l & 15);
        int ibase = m0 + wr + mi * 16 + (l >> 4) * 4;
#pragma unroll
        for (int r = 0; r < 4; ++r)
          Ob[(size_t)(ibase + r) * CC + col] = acc[mi][ni][r];
      }
    }
  } else {
    // partial rows: global row ibase in [1024,2048) -> part row ibase-1024
    float* Pb = part + (size_t)b * 1024 * CC;
#pragma unroll
    for (int mi = 0; mi < 4; ++mi) {
#pragma unroll
      for (int ni = 0; ni < 4; ++ni) {
        int col = n0 + wc + ni * 16 + (l & 15);
        int ibase = m0 + wr + mi * 16 + (l >> 4) * 4 - 1024;
#pragma unroll
        for (int r = 0; r < 4; ++r)
          Pb[(size_t)(ibase + r) * CC + col] = acc[mi][ni][r];
      }
    }
  }
}

// ---------------------------------------------------------------------------
// Kernel 7: combine — out rows [1024,2048) per batch += part.  float4 per
// thread; 4b x 1024 rows x 192 f4/row = 786432 f4 / 256 = 3072 blocks.
// ---------------------------------------------------------------------------
__global__ __launch_bounds__(256) void combine_kernel(
    const float* __restrict__ part, float* __restrict__ out) {
  int i = blockIdx.x * 256 + threadIdx.x;  // float4 id
  int b = i / (1024 * 192);
  int rem = i - b * 1024 * 192;
  int row = rem / 192;
  int c4 = rem - row * 192;
  const float4* p4 = (const float4*)part;
  float4 pv = p4[i];
  float4* o4 = (float4*)(out + ((size_t)b * TT + 1024 + row) * CC) + c4;
  float4 ov = *o4;
  ov.x += pv.x; ov.y += pv.y; ov.z += pv.z; ov.w += pv.w;
  *o4 = ov;
}

// ---------------------------------------------------------------------------
extern "C" void kernel_launch(void* const* d_in, const int* in_sizes, int n_in,
                              void* d_out, int out_size, void* d_ws,
                              size_t ws_size, hipStream_t stream) {
  const float* x = (const float*)d_in[0];
  const float* Wq = (const float*)d_in[1];
  const float* bq = (const float*)d_in[2];
  const float* Wk = (const float*)d_in[3];
  const float* bk = (const float*)d_in[4];
  const float* Wv = (const float*)d_in[5];
  const float* bv = (const float*)d_in[6];
  float* out = (float*)d_out;

  char* ws = (char*)d_ws;
  size_t off = 0;
  auto carve = [&](size_t bytes) -> char* {
    char* p = ws + off;
    off += (bytes + 255) & ~(size_t)255;
    return p;
  };
  const size_t M = (size_t)BB * TT;  // 8192
  bf16_t* xbf = (bf16_t*)carve(M * CC * 2);            // 12.6 MB
  bf16_t* wt  = (bf16_t*)carve(3ull * CC * CC * 2);    // 3.5 MB
  bf16_t* qb  = (bf16_t*)carve(M * CC * 2);            // 12.6 MB
  bf16_t* kb  = (bf16_t*)carve(M * CC * 2);            // 12.6 MB
  bf16_t* vt  = (bf16_t*)carve(M * CC * 2);            // 12.6 MB (as [B][H][T])
  _Float16* S = (_Float16*)carve((size_t)BB * TT * TT * 2);  // 33.5 MB
  bf16_t* P   = (bf16_t*)carve((size_t)BB * TT * TT * 2);    // 33.5 MB
  float* part = (float*)carve((size_t)BB * 1024 * CC * 4);   // 12.6 MB
  (void)off; (void)ws_size;

  // 1+2: input prep
  cast_x_kernel<<<(M * CC / 8 + 255) / 256, 256, 0, stream>>>(x, xbf);
  transpose_w_kernel<<<dim3(CC / 32, CC / 32, 3), dim3(32, 8, 1), 0, stream>>>(
      Wq, Wk, Wv, wt);
  // 3: q,k,v
  qkv_gemm_kernel<<<1152, 256, 0, stream>>>(xbf, wt, bq, bk, bv, qb, kb, vt);
  // 4: S = q k^T (lower-tri blocks, fp16)
  s_gemm_kernel<<<544, 256, 0, stream>>>(qb, kb, S);
  // 5: softmax rows -> P (bf16, zero-padded)
  rowstat_kernel<<<BB * TT / 4, 256, 0, stream>>>(S, P);
  // 6: O = P V (split-K heavy half)
  o_gemm_kernel<<<576, 256, 0, stream>>>(P, vt, out, part);
  // 7: combine partials into out rows [1024,2048) per batch
  combine_kernel<<<3072, 256, 0, stream>>>(part, out);
}

// Round 15
// 197.913 us; speedup vs baseline: 1.0237x; 1.0237x over previous
//
#include <hip/hip_runtime.h>
#include <math.h>

// ---------------------------------------------------------------------------
// AttentionLayer: out = softmax(mask(q k^T * scale)) @ v,  q/k/v = x@W + b
// B=4, T=2048, C=H=768.  bf16 MFMA (16x16x32), fp32 accumulate.
// R18 = exact revert to R16/R9 (session best: 197.3/199.0 us).  Split-K arc
//     (R17) closed per precommitted rule: 202.6 >= 199.  Post-mortem: the
//     12.6MB partial round-trip + combine launch + re-paid prologues ate the
//     crit-path savings; split-K only pays when split work >> partial I/O.
// Measured-negative arcs this session (all reverted): counted-vmcnt
//     pipelines (R5/R6), qkv launch_bounds(,4) (R8), q/k LDS epilogues
//     (R10), fused softmax (R12-R15), split-K o (R17).
// Config: R3 static-dbuf gemm_core (32KB LDS, plain __syncthreads);
//     XCD-chunked 1D grids; qkv (256) direct q/k stores + LDS-coalesced vt;
//     s_gemm (256,4) live-tri grid; wave-per-row rowstat; o_gemm (256,4)
//     balance-paired, causal-truncated K.
// ---------------------------------------------------------------------------

#define BB 4
#define TT 2048
#define CC 768

typedef __bf16 bf16_t;
typedef __bf16 bf16x8 __attribute__((ext_vector_type(8)));
typedef _Float16 half8 __attribute__((ext_vector_type(8)));
typedef float f32x4 __attribute__((ext_vector_type(4)));

// ---------------------------------------------------------------------------
// async global->LDS 16B copy (wave-uniform LDS base + lane*16 implicit)
// ---------------------------------------------------------------------------
__device__ __forceinline__ void async_load16(void* lds, const void* g) {
  __builtin_amdgcn_global_load_lds(
      (const __attribute__((address_space(1))) void*)g,
      (__attribute__((address_space(3))) void*)lds, 16, 0, 0);
}

// Chunk swizzle for a 128x32 bf16 tile stored as 4x16B chunks per 64B row.
__device__ __forceinline__ int swz4(int r) {
  return (r & 3) ^ ((r >> 2) & 3);
}

// Stage a 128x32 bf16 tile (row-major, row stride ld elements) into LDS.
__device__ __forceinline__ void stage_tile(const bf16_t* __restrict__ g0,
                                           int ld, bf16_t* lds, int t) {
  int w = t >> 6, l = t & 63;
#pragma unroll
  for (int i = 0; i < 2; ++i) {
    int c = i * 256 + w * 64 + l;   // linear 16B-chunk id in LDS
    int row = c >> 2;
    int p = c & 3;
    int q = p ^ swz4(row);          // logical chunk to fetch
    async_load16(lds + i * 2048 + w * 512,  // wave-uniform base (elements)
                 g0 + row * ld + q * 8);
  }
}

// Read one MFMA fragment (8 bf16, 16B) for logical (row r, k-chunk q).
__device__ __forceinline__ bf16x8 read_frag(const bf16_t* lds, int r, int q) {
  int p = q ^ swz4(r);
  return *(const bf16x8*)(lds + r * 32 + p * 8);
}

// One 128x128x32 MFMA step from a published LDS buffer pair.
__device__ __forceinline__ void mfma_tile(const bf16_t* Ab, const bf16_t* Bb,
                                          int wr, int wc, int l,
                                          f32x4 acc[4][4]) {
  bf16x8 af[4], bfr[4];
  int q = l >> 4;
#pragma unroll
  for (int i = 0; i < 4; ++i) {
    af[i] = read_frag(Ab, wr + i * 16 + (l & 15), q);
    bfr[i] = read_frag(Bb, wc + i * 16 + (l & 15), q);
  }
#pragma unroll
  for (int mi = 0; mi < 4; ++mi)
#pragma unroll
    for (int ni = 0; ni < 4; ++ni)
      acc[mi][ni] = __builtin_amdgcn_mfma_f32_16x16x32_bf16(
          af[mi], bfr[ni], acc[mi][ni], 0, 0, 0);
}

// Core: C[128x128] += A[128xK] * B^T.  kTiles must be EVEN.
// R3-proven unroll-2 static double-buffer: one barrier per k-tile; each async
// stage has a full MFMA phase in flight before the barrier that drains it.
// Plain __syncthreads (compiler manages waitcnt); 32 KB LDS.
__device__ __forceinline__ void gemm_core(const bf16_t* __restrict__ A, int lda,
                                          const bf16_t* __restrict__ B, int ldb,
                                          int kTiles, bf16_t* As0, bf16_t* As1,
                                          bf16_t* Bs0, bf16_t* Bs1,
                                          f32x4 acc[4][4]) {
  int t = threadIdx.x;
  int l = t & 63;
  int w = t >> 6;
  int wr = (w >> 1) * 64;  // wave row offset in 128-tile
  int wc = (w & 1) * 64;   // wave col offset

  stage_tile(A, lda, As0, t);  // k-tile 0 -> buf0
  stage_tile(B, ldb, Bs0, t);

  for (int kt = 0; kt < kTiles; kt += 2) {
    __syncthreads();  // publish buf0(kt); prior buf1 reads complete
    stage_tile(A + (kt + 1) * 32, lda, As1, t);   // prefetch kt+1
    stage_tile(B + (kt + 1) * 32, ldb, Bs1, t);
    mfma_tile(As0, Bs0, wr, wc, l, acc);
    __syncthreads();  // publish buf1(kt+1); buf0 reads complete
    if (kt + 2 < kTiles) {
      stage_tile(A + (kt + 2) * 32, lda, As0, t);  // prefetch kt+2
      stage_tile(B + (kt + 2) * 32, ldb, Bs0, t);
    }
    mfma_tile(As1, Bs1, wr, wc, l, acc);
  }
}

// C/D layout (m89-verified): col = lane&15, row = (lane>>4)*4 + reg.

// ---------------------------------------------------------------------------
// Kernel 1: cast x (fp32) -> bf16, 8 elems/thread
// ---------------------------------------------------------------------------
__global__ __launch_bounds__(256) void cast_x_kernel(
    const float* __restrict__ x, bf16_t* __restrict__ xbf) {
  int i = blockIdx.x * 256 + threadIdx.x;
  const float4* xin = (const float4*)x;
  float4 a = xin[i * 2];
  float4 b = xin[i * 2 + 1];
  bf16_t tmp[8];
  tmp[0] = (bf16_t)a.x; tmp[1] = (bf16_t)a.y;
  tmp[2] = (bf16_t)a.z; tmp[3] = (bf16_t)a.w;
  tmp[4] = (bf16_t)b.x; tmp[5] = (bf16_t)b.y;
  tmp[6] = (bf16_t)b.z; tmp[7] = (bf16_t)b.w;
  *(uint4*)(xbf + (size_t)i * 8) = *(const uint4*)tmp;
}

// ---------------------------------------------------------------------------
// Kernel 2: transpose+cast the three weight matrices [C][H] -> bf16 [H][C]
// ---------------------------------------------------------------------------
__global__ __launch_bounds__(256) void transpose_w_kernel(
    const float* __restrict__ Wq, const float* __restrict__ Wk,
    const float* __restrict__ Wv, bf16_t* __restrict__ wt) {
  int z = blockIdx.z;
  const float* W = (z == 0) ? Wq : (z == 1) ? Wk : Wv;
  bf16_t* out = wt + (size_t)z * CC * CC;
  __shared__ float tile[32][33];
  int tx = threadIdx.x;  // 0..31
  int ty = threadIdx.y;  // 0..7
  int n0 = blockIdx.x * 32;
  int c0 = blockIdx.y * 32;
#pragma unroll
  for (int k = 0; k < 4; ++k)
    tile[ty + k * 8][tx] = W[(size_t)(c0 + ty + k * 8) * CC + n0 + tx];
  __syncthreads();
#pragma unroll
  for (int k = 0; k < 4; ++k)
    out[(size_t)(n0 + ty + k * 8) * CC + c0 + tx] =
        (bf16_t)tile[tx][ty + k * 8];
}

// ---------------------------------------------------------------------------
// Kernel 3: QKV GEMM, 1D grid of 1152 = 8 XCD chunks x 144.
// Chunk-local order: n fastest within an m-row -> the 6 blocks sharing an
// A m-tile run consecutively on ONE XCD (L2 catches the re-reads).
// z=0: q (scaled by H^-1/2, direct stores), z=1: k (direct stores),
// z=2: v transposed (LDS-coalesced 16B stores).
// ---------------------------------------------------------------------------
__global__ __launch_bounds__(256) void qkv_gemm_kernel(
    const bf16_t* __restrict__ xbf, const bf16_t* __restrict__ wt,
    const float* __restrict__ bq, const float* __restrict__ bk,
    const float* __restrict__ bv, bf16_t* __restrict__ qb,
    bf16_t* __restrict__ kb, bf16_t* __restrict__ vt) {
  __shared__ bf16_t smem[16384];  // 32KB: gemm dbuf, then vt transpose buf
  int bid = blockIdx.x;
  int work = (bid & 7) * 144 + (bid >> 3);  // 1152 = 8 * 144 (bijective)
  int z = work / 384;
  int rw = work - z * 384;
  int m0 = (rw / 6) * 128;
  int n0 = (rw % 6) * 128;

  f32x4 acc[4][4];
#pragma unroll
  for (int i = 0; i < 4; ++i)
#pragma unroll
    for (int j = 0; j < 4; ++j) acc[i][j] = (f32x4){0.f, 0.f, 0.f, 0.f};

  const bf16_t* A = xbf + (size_t)m0 * CC;
  const bf16_t* B = wt + (size_t)z * CC * CC + (size_t)n0 * CC;
  gemm_core(A, CC, B, CC, CC / 32, smem, smem + 4096, smem + 8192,
            smem + 12288, acc);

  int t = threadIdx.x;
  int l = t & 63, w = t >> 6;
  int wr = (w >> 1) * 64, wc = (w & 1) * 64;
  const float* bias = (z == 0) ? bq : (z == 1) ? bk : bv;

  if (z < 2) {
    float scale = (z == 0) ? rsqrtf((float)CC) : 1.0f;
    bf16_t* dst = (z == 0) ? qb : kb;
#pragma unroll
    for (int mi = 0; mi < 4; ++mi) {
#pragma unroll
      for (int ni = 0; ni < 4; ++ni) {
        int col = n0 + wc + ni * 16 + (l & 15);
        int rbase = m0 + wr + mi * 16 + (l >> 4) * 4;
        float bcol = bias[col];
#pragma unroll
        for (int r = 0; r < 4; ++r) {
          float v = (acc[mi][ni][r] + bcol) * scale;
          dst[(size_t)(rbase + r) * CC + col] = (bf16_t)v;
        }
      }
    }
  } else {
    // v^T: stage as [col][m] (chunk-XOR), write 16B/lane along T.
    __syncthreads();  // all waves done reading gemm LDS buffers
#pragma unroll
    for (int mi = 0; mi < 4; ++mi) {
#pragma unroll
      for (int ni = 0; ni < 4; ++ni) {
        int cl = wc + ni * 16 + (l & 15);
        int mlb = wr + mi * 16 + (l >> 4) * 4;
        float bcol = bias[n0 + cl];
        bf16_t t4[4];
#pragma unroll
        for (int r = 0; r < 4; ++r) t4[r] = (bf16_t)(acc[mi][ni][r] + bcol);
        int e = cl * 128 + (((mlb >> 3) ^ (cl & 15)) << 3) + (mlb & 7);
        *(uint2*)((unsigned int*)smem + (e >> 1)) = *(const uint2*)t4;
      }
    }
    __syncthreads();
    int b = m0 >> 11;
    int tt0 = m0 & (TT - 1);
#pragma unroll
    for (int g = 0; g < 8; ++g) {
      int cl = g * 16 + (t >> 4);
      int ck = t & 15;
      int phys = ck ^ (cl & 15);
      uint4 v = *(const uint4*)(smem + cl * 128 + phys * 8);
      *(uint4*)(vt + ((size_t)b * CC + n0 + cl) * TT + tt0 + ck * 8) = v;
    }
  }
}

// ---------------------------------------------------------------------------
// Kernel 4: S = q k^T (scale folded into q), causal mask + (==0 -> -inf),
// stored fp16.  1D grid of 544 LIVE lower-tri blocks = 8 XCD chunks x 68;
// triangular decode (guarded sqrt).  Same-ti blocks consecutive -> q-tile
// L2 reuse.
// ---------------------------------------------------------------------------
__global__ __launch_bounds__(256, 4) void s_gemm_kernel(
    const bf16_t* __restrict__ qb, const bf16_t* __restrict__ kb,
    _Float16* __restrict__ S) {
  __shared__ bf16_t As0[4096], As1[4096], Bs0[4096], Bs1[4096];
  int bid = blockIdx.x;
  int work = (bid & 7) * 68 + (bid >> 3);  // 544 = 8 * 68 (bijective)
  int b = work / 136;
  int t = work - b * 136;
  int ti = (int)((sqrtf(8.f * (float)t + 1.f) - 1.f) * 0.5f);
  while ((ti + 1) * (ti + 2) / 2 <= t) ++ti;  // guard fp rounding
  while (ti * (ti + 1) / 2 > t) --ti;
  int tj = t - ti * (ti + 1) / 2;
  int m0 = ti * 128, n0 = tj * 128;

  f32x4 acc[4][4];
#pragma unroll
  for (int i = 0; i < 4; ++i)
#pragma unroll
    for (int j = 0; j < 4; ++j) acc[i][j] = (f32x4){0.f, 0.f, 0.f, 0.f};

  const bf16_t* A = qb + ((size_t)b * TT + m0) * CC;
  const bf16_t* B = kb + ((size_t)b * TT + n0) * CC;
  gemm_core(A, CC, B, CC, CC / 32, As0, As1, Bs0, Bs1, acc);

  _Float16* Sb = S + (size_t)b * TT * TT;
  int l = threadIdx.x & 63, w = threadIdx.x >> 6;
  int wr = (w >> 1) * 64, wc = (w & 1) * 64;
#pragma unroll
  for (int mi = 0; mi < 4; ++mi) {
#pragma unroll
    for (int ni = 0; ni < 4; ++ni) {
      int j = n0 + wc + ni * 16 + (l & 15);
      int ibase = m0 + wr + mi * 16 + (l >> 4) * 4;
#pragma unroll
      for (int r = 0; r < 4; ++r) {
        int i = ibase + r;
        float v = acc[mi][ni][r];
        if (j > i || v == 0.0f) v = -INFINITY;  // causal + reference quirk
        Sb[(size_t)i * TT + j] = (_Float16)v;
      }
    }
  }
}

// ---------------------------------------------------------------------------
// Kernel 5: rowstat+normalize, wave-per-row (no LDS, no barriers).
// Block = 4 waves = 4 rows.  Per row: max M, L = sum exp(s-M); writes
// P = exp(s-M)/L as bf16 up to the 128-padded causal length.
// Lane l covers chunks {l, l+64, l+128, l+192} of 8 fp16 each.
// ---------------------------------------------------------------------------
__global__ __launch_bounds__(256) void rowstat_kernel(
    const _Float16* __restrict__ S, bf16_t* __restrict__ P) {
  int g = blockIdx.x * 4 + (threadIdx.x >> 6);  // global row id
  int b = g >> 11;
  int row = g & (TT - 1);
  int l = threadIdx.x & 63;
  const _Float16* s = S + ((size_t)b * TT + row) * TT;
  bf16_t* p = P + ((size_t)b * TT + row) * TT;
  int pe = ((row >> 7) + 1) << 7;  // padded causal length, multiple of 128

  float f[4][8];
#pragma unroll
  for (int c = 0; c < 4; ++c) {
    int j = (c * 64 + l) * 8;
    if (j < pe) {
      half8 h = *(const half8*)(s + j);
#pragma unroll
      for (int k = 0; k < 8; ++k) f[c][k] = (float)h[k];
    } else {
#pragma unroll
      for (int k = 0; k < 8; ++k) f[c][k] = -INFINITY;
    }
  }

  float m = f[0][0];
#pragma unroll
  for (int c = 0; c < 4; ++c)
#pragma unroll
    for (int k = 0; k < 8; ++k) m = fmaxf(m, f[c][k]);
#pragma unroll
  for (int off = 32; off > 0; off >>= 1) m = fmaxf(m, __shfl_xor(m, off));

  float e[4][8];
  float sum = 0.f;
#pragma unroll
  for (int c = 0; c < 4; ++c)
#pragma unroll
    for (int k = 0; k < 8; ++k) {
      e[c][k] = __expf(f[c][k] - m);  // exp(-inf)=0 for masked slots
      sum += e[c][k];
    }
#pragma unroll
  for (int off = 32; off > 0; off >>= 1) sum += __shfl_xor(sum, off);
  float inv = 1.0f / sum;

#pragma unroll
  for (int c = 0; c < 4; ++c) {
    int j = (c * 64 + l) * 8;
    if (j < pe) {
      bf16x8 o;
#pragma unroll
      for (int k = 0; k < 8; ++k) o[k] = (bf16_t)(e[c][k] * inv);
      *(bf16x8*)(p + j) = o;
    }
  }
}

// ---------------------------------------------------------------------------
// Kernel 6: O = P @ V   (A = P row-major [T][T], Bt = v^T [B][H][T]).
// 1D grid of 384 = 8 XCD chunks x 48.  Within a chunk: nj fastest (A-tile
// reuse), ti from the balance-paired permutation {15,0,14,1,...} so every
// chunk gets equal causal K work; heavy tiles lead each chunk.
// K-loop truncated at the causal boundary.
// ---------------------------------------------------------------------------
__global__ __launch_bounds__(256, 4) void o_gemm_kernel(
    const bf16_t* __restrict__ P, const bf16_t* __restrict__ vt,
    float* __restrict__ out) {
  __shared__ bf16_t As0[4096], As1[4096], Bs0[4096], Bs1[4096];
  int bid = blockIdx.x;
  int work = (bid & 7) * 48 + (bid >> 3);  // 384 = 8 * 48 (bijective)
  int b = work / 96;
  int rw = work - b * 96;
  int i = rw / 6, nj = rw % 6;
  int ti = (i & 1) ? ((i - 1) >> 1) : (15 - (i >> 1));  // 15,0,14,1,...,8,7
  int m0 = ti * 128, n0 = nj * 128;

  f32x4 acc[4][4];
#pragma unroll
  for (int ii = 0; ii < 4; ++ii)
#pragma unroll
    for (int j = 0; j < 4; ++j) acc[ii][j] = (f32x4){0.f, 0.f, 0.f, 0.f};

  const bf16_t* A = P + ((size_t)b * TT + m0) * TT;
  const bf16_t* B = vt + ((size_t)b * CC + n0) * TT;
  gemm_core(A, TT, B, TT, (ti + 1) * 4, As0, As1, Bs0, Bs1, acc);

  float* Ob = out + (size_t)b * TT * CC;
  int l = threadIdx.x & 63, w = threadIdx.x >> 6;
  int wr = (w >> 1) * 64, wc = (w & 1) * 64;
#pragma unroll
  for (int mi = 0; mi < 4; ++mi) {
#pragma unroll
    for (int ni = 0; ni < 4; ++ni) {
      int col = n0 + wc + ni * 16 + (l & 15);
      int ibase = m0 + wr + mi * 16 + (l >> 4) * 4;
#pragma unroll
      for (int r = 0; r < 4; ++r)
        Ob[(size_t)(ibase + r) * CC + col] = acc[mi][ni][r];
    }
  }
}

// ---------------------------------------------------------------------------
extern "C" void kernel_launch(void* const* d_in, const int* in_sizes, int n_in,
                              void* d_out, int out_size, void* d_ws,
                              size_t ws_size, hipStream_t stream) {
  const float* x = (const float*)d_in[0];
  const float* Wq = (const float*)d_in[1];
  const float* bq = (const float*)d_in[2];
  const float* Wk = (const float*)d_in[3];
  const float* bk = (const float*)d_in[4];
  const float* Wv = (const float*)d_in[5];
  const float* bv = (const float*)d_in[6];
  float* out = (float*)d_out;

  char* ws = (char*)d_ws;
  size_t off = 0;
  auto carve = [&](size_t bytes) -> char* {
    char* p = ws + off;
    off += (bytes + 255) & ~(size_t)255;
    return p;
  };
  const size_t M = (size_t)BB * TT;  // 8192
  bf16_t* xbf = (bf16_t*)carve(M * CC * 2);            // 12.6 MB
  bf16_t* wt  = (bf16_t*)carve(3ull * CC * CC * 2);    // 3.5 MB
  bf16_t* qb  = (bf16_t*)carve(M * CC * 2);            // 12.6 MB
  bf16_t* kb  = (bf16_t*)carve(M * CC * 2);            // 12.6 MB
  bf16_t* vt  = (bf16_t*)carve(M * CC * 2);            // 12.6 MB (as [B][H][T])
  _Float16* S = (_Float16*)carve((size_t)BB * TT * TT * 2);  // 33.5 MB
  bf16_t* P   = (bf16_t*)carve((size_t)BB * TT * TT * 2);    // 33.5 MB
  (void)off; (void)ws_size;

  // 1+2: input prep
  cast_x_kernel<<<(M * CC / 8 + 255) / 256, 256, 0, stream>>>(x, xbf);
  transpose_w_kernel<<<dim3(CC / 32, CC / 32, 3), dim3(32, 8, 1), 0, stream>>>(
      Wq, Wk, Wv, wt);
  // 3: q,k,v
  qkv_gemm_kernel<<<1152, 256, 0, stream>>>(xbf, wt, bq, bk, bv, qb, kb, vt);
  // 4: S = q k^T (lower-tri blocks, fp16)
  s_gemm_kernel<<<544, 256, 0, stream>>>(qb, kb, S);
  // 5: softmax rows -> P (bf16, zero-padded)
  rowstat_kernel<<<BB * TT / 4, 256, 0, stream>>>(S, P);
  // 6: O = P V
  o_gemm_kernel<<<384, 256, 0, stream>>>(P, vt, out);
}